// Round 2
// baseline (2916.399 us; speedup 1.0000x reference)
//
#include <hip/hip_runtime.h>

#define D_MODEL 1024
#define NUM_HEADS 16
#define D_HEAD 64
#define BATCH 2
#define SEQ 2048
#define MTOT (BATCH * SEQ) /* 4096 */

// ---------- bf16 helpers (raw ushort) ----------
__device__ __forceinline__ unsigned short f2bf(float f) {
  union { float f; unsigned int i; } v; v.f = f;
  unsigned int r = v.i + 0x7FFFu + ((v.i >> 16) & 1u); // RNE
  return (unsigned short)(r >> 16);
}
// unpack 8 bf16 (uint4) -> 8 floats
__device__ __forceinline__ void unpack8(uint4 v, float* dst) {
  unsigned int w[4] = {v.x, v.y, v.z, v.w};
#pragma unroll
  for (int i = 0; i < 4; ++i) {
    union { unsigned int u; float f; } a, b;
    a.u = w[i] << 16;          dst[2 * i]     = a.f;
    b.u = w[i] & 0xFFFF0000u;  dst[2 * i + 1] = b.f;
  }
}

// ---------- GEMM: C(M,N) = A(M,K) * B(N,K)^T, fp32 acc ----------
// ABF/BBF/CBF select bf16 (true) or f32 (false) for A/B/C storage.
#define BM 128
#define BN 128
#define BK 16

template <bool ABF, bool BBF, bool CBF>
__global__ __launch_bounds__(256) void gemm_bt(const void* __restrict__ Av,
                                               const void* __restrict__ Bv,
                                               void* __restrict__ Cv,
                                               int M, int N, int K) {
  __shared__ float As[BK][BM + 1];
  __shared__ float Bs[BK][BN + 1];
  const int tid = threadIdx.x;
  const int bm = blockIdx.y * BM;
  const int bn = blockIdx.x * BN;
  const int tx = tid & 15;   // col group
  const int ty = tid >> 4;   // row group
  const int lr = tid >> 1;         // 0..127 staging row
  const int lc = (tid & 1) * 8;    // 0 or 8 staging col

  float acc[8][8];
#pragma unroll
  for (int i = 0; i < 8; ++i)
#pragma unroll
    for (int j = 0; j < 8; ++j) acc[i][j] = 0.f;

  for (int k0 = 0; k0 < K; k0 += BK) {
    float fa[8], fb[8];
    if constexpr (ABF) {
      const unsigned short* p = (const unsigned short*)Av + (size_t)(bm + lr) * K + lc + k0;
      unpack8(*(const uint4*)p, fa);
    } else {
      const float* p = (const float*)Av + (size_t)(bm + lr) * K + lc + k0;
      float4 v0 = *(const float4*)p;
      float4 v1 = *(const float4*)(p + 4);
      fa[0] = v0.x; fa[1] = v0.y; fa[2] = v0.z; fa[3] = v0.w;
      fa[4] = v1.x; fa[5] = v1.y; fa[6] = v1.z; fa[7] = v1.w;
    }
    if constexpr (BBF) {
      const unsigned short* p = (const unsigned short*)Bv + (size_t)(bn + lr) * K + lc + k0;
      unpack8(*(const uint4*)p, fb);
    } else {
      const float* p = (const float*)Bv + (size_t)(bn + lr) * K + lc + k0;
      float4 v0 = *(const float4*)p;
      float4 v1 = *(const float4*)(p + 4);
      fb[0] = v0.x; fb[1] = v0.y; fb[2] = v0.z; fb[3] = v0.w;
      fb[4] = v1.x; fb[5] = v1.y; fb[6] = v1.z; fb[7] = v1.w;
    }
#pragma unroll
    for (int j = 0; j < 8; ++j) As[lc + j][lr] = fa[j];
#pragma unroll
    for (int j = 0; j < 8; ++j) Bs[lc + j][lr] = fb[j];
    __syncthreads();
#pragma unroll
    for (int kk = 0; kk < BK; ++kk) {
      float a[8], b[8];
#pragma unroll
      for (int i = 0; i < 8; ++i) a[i] = As[kk][ty + 16 * i];
#pragma unroll
      for (int j = 0; j < 8; ++j) b[j] = Bs[kk][tx + 16 * j];
#pragma unroll
      for (int i = 0; i < 8; ++i)
#pragma unroll
        for (int j = 0; j < 8; ++j) acc[i][j] += a[i] * b[j];
    }
    __syncthreads();
  }

#pragma unroll
  for (int i = 0; i < 8; ++i) {
    const int row = bm + ty + 16 * i;
    if constexpr (CBF) {
      unsigned short* cp = (unsigned short*)Cv + (size_t)row * N + bn + tx;
#pragma unroll
      for (int j = 0; j < 8; ++j) cp[16 * j] = f2bf(acc[i][j]);
    } else {
      float* cp = (float*)Cv + (size_t)row * N + bn + tx;
#pragma unroll
      for (int j = 0; j < 8; ++j) cp[16 * j] = acc[i][j];
    }
  }
}

// ---------- causal flash attention, one thread per query row (bf16 I/O) ----------
#define TQ 128
#define TK 32

__global__ __launch_bounds__(128) void attn_fwd(const unsigned short* __restrict__ Qb,
                                                const unsigned short* __restrict__ Kb,
                                                const unsigned short* __restrict__ Vb,
                                                unsigned short* __restrict__ Ob) {
  const int b = blockIdx.z;
  const int h = blockIdx.y;
  const int q0 = blockIdx.x * TQ;
  const int t = threadIdx.x;
  const int s = q0 + t;

  __shared__ float Ks[TK][64];
  __shared__ float Vs[TK][64];

  // load q row, pre-scaled by 1/sqrt(dh) = 0.125
  float q[64];
  {
    const unsigned short* qp = Qb + ((size_t)(b * SEQ + s) * D_MODEL + h * D_HEAD);
#pragma unroll
    for (int d8 = 0; d8 < 8; ++d8) {
      float tmp[8];
      unpack8(*(const uint4*)(qp + d8 * 8), tmp);
#pragma unroll
      for (int i = 0; i < 8; ++i) q[d8 * 8 + i] = tmp[i] * 0.125f;
    }
  }

  float o[64];
#pragma unroll
  for (int d = 0; d < 64; ++d) o[d] = 0.f;
  float m = -INFINITY, l = 0.f;

  const int kend = q0 + TQ;          // keys needed by this block (exclusive)
  const int flat = t * 16;           // 128 threads * 16 elems = 32*64 tile
  const int row = flat >> 6;
  const int col = flat & 63;

  for (int k0 = 0; k0 < kend; k0 += TK) {
    __syncthreads();  // previous tile fully consumed
    {
      const unsigned short* kp = Kb + ((size_t)(b * SEQ + k0 + row) * D_MODEL + h * D_HEAD + col);
      const unsigned short* vp = Vb + ((size_t)(b * SEQ + k0 + row) * D_MODEL + h * D_HEAD + col);
      unpack8(*(const uint4*)(kp),     &Ks[row][col]);
      unpack8(*(const uint4*)(kp + 8), &Ks[row][col + 8]);
      unpack8(*(const uint4*)(vp),     &Vs[row][col]);
      unpack8(*(const uint4*)(vp + 8), &Vs[row][col + 8]);
    }
    __syncthreads();

#pragma unroll 1
    for (int j = 0; j < TK; ++j) {
      const int k = k0 + j;
      if (k > s) break;  // causal; loop exit only — barriers are outside
      const float4* kr = (const float4*)(&Ks[j][0]);
      float sc = 0.f;
#pragma unroll
      for (int dd = 0; dd < 16; ++dd) {
        float4 kv = kr[dd];
        sc += q[dd * 4 + 0] * kv.x;
        sc += q[dd * 4 + 1] * kv.y;
        sc += q[dd * 4 + 2] * kv.z;
        sc += q[dd * 4 + 3] * kv.w;
      }
      const float4* vr = (const float4*)(&Vs[j][0]);
      if (sc <= m) {
        float e = __expf(sc - m);
        l += e;
#pragma unroll
        for (int dd = 0; dd < 16; ++dd) {
          float4 vv = vr[dd];
          o[dd * 4 + 0] += e * vv.x;
          o[dd * 4 + 1] += e * vv.y;
          o[dd * 4 + 2] += e * vv.z;
          o[dd * 4 + 3] += e * vv.w;
        }
      } else {
        float c = __expf(m - sc);  // exp(-inf)=0 handles first key
        m = sc;
        l = l * c + 1.f;
#pragma unroll
        for (int dd = 0; dd < 16; ++dd) {
          float4 vv = vr[dd];
          o[dd * 4 + 0] = o[dd * 4 + 0] * c + vv.x;
          o[dd * 4 + 1] = o[dd * 4 + 1] * c + vv.y;
          o[dd * 4 + 2] = o[dd * 4 + 2] * c + vv.z;
          o[dd * 4 + 3] = o[dd * 4 + 3] * c + vv.w;
        }
      }
    }
  }

  const float inv = 1.f / l;
  unsigned short* op = Ob + ((size_t)(b * SEQ + s) * D_MODEL + h * D_HEAD);
#pragma unroll
  for (int d8 = 0; d8 < 8; ++d8) {
    uint4 pk;
    pk.x = (unsigned int)f2bf(o[d8 * 8 + 0] * inv) | ((unsigned int)f2bf(o[d8 * 8 + 1] * inv) << 16);
    pk.y = (unsigned int)f2bf(o[d8 * 8 + 2] * inv) | ((unsigned int)f2bf(o[d8 * 8 + 3] * inv) << 16);
    pk.z = (unsigned int)f2bf(o[d8 * 8 + 4] * inv) | ((unsigned int)f2bf(o[d8 * 8 + 5] * inv) << 16);
    pk.w = (unsigned int)f2bf(o[d8 * 8 + 6] * inv) | ((unsigned int)f2bf(o[d8 * 8 + 7] * inv) << 16);
    *(uint4*)(op + d8 * 8) = pk;
  }
}

extern "C" void kernel_launch(void* const* d_in, const int* in_sizes, int n_in,
                              void* d_out, int out_size, void* d_ws, size_t ws_size,
                              hipStream_t stream) {
  const float* x  = (const float*)d_in[0];
  const float* Wq = (const float*)d_in[1];
  const float* Wk = (const float*)d_in[2];
  const float* Wv = (const float*)d_in[3];
  const float* Wo = (const float*)d_in[4];

  const size_t PLANE = (size_t)MTOT * D_MODEL;  // 4M elems
  unsigned short* Qb = (unsigned short*)d_ws;   // bf16 intermediates (32 MB total)
  unsigned short* Kb = Qb + PLANE;
  unsigned short* Vb = Kb + PLANE;
  unsigned short* Ab = Vb + PLANE;
  float* out = (float*)d_out;

  dim3 gg(D_MODEL / BN, MTOT / BM);  // (8, 32)
  gemm_bt<false, false, true><<<gg, 256, 0, stream>>>(x, Wq, Qb, MTOT, D_MODEL, D_MODEL);
  gemm_bt<false, false, true><<<gg, 256, 0, stream>>>(x, Wk, Kb, MTOT, D_MODEL, D_MODEL);
  gemm_bt<false, false, true><<<gg, 256, 0, stream>>>(x, Wv, Vb, MTOT, D_MODEL, D_MODEL);
  attn_fwd<<<dim3(SEQ / TQ, NUM_HEADS, BATCH), TQ, 0, stream>>>(Qb, Kb, Vb, Ab);
  gemm_bt<true, false, false><<<gg, 256, 0, stream>>>(Ab, Wo, out, MTOT, D_MODEL, D_MODEL);
}

// Round 3
// 1166.280 us; speedup vs baseline: 2.5006x; 2.5006x over previous
//
#include <hip/hip_runtime.h>

#define D_MODEL 1024
#define NUM_HEADS 16
#define D_HEAD 64
#define BATCH 2
#define SEQ 2048
#define MTOT (BATCH * SEQ) /* 4096 */
#define PLANE ((size_t)MTOT * D_MODEL)

typedef unsigned short us;
typedef __bf16 bf16x8 __attribute__((ext_vector_type(8)));
typedef float floatx4 __attribute__((ext_vector_type(4)));

// ---------- bf16 helpers ----------
__device__ __forceinline__ unsigned int f2bf(float f) {
  union { float f; unsigned int i; } v; v.f = f;
  unsigned int r = v.i + 0x7FFFu + ((v.i >> 16) & 1u); // RNE
  return r >> 16;
}
__device__ __forceinline__ void unpack8(uint4 v, float* dst) {
  unsigned int w[4] = {v.x, v.y, v.z, v.w};
#pragma unroll
  for (int i = 0; i < 4; ++i) {
    union { unsigned int u; float f; } a, b;
    a.u = w[i] << 16;          dst[2 * i]     = a.f;
    b.u = w[i] & 0xFFFF0000u;  dst[2 * i + 1] = b.f;
  }
}

// ---------- f32 -> bf16 conversion ----------
__global__ __launch_bounds__(256) void convert_bf16(const float* __restrict__ src,
                                                    us* __restrict__ dst, int n4) {
  int i = blockIdx.x * 256 + threadIdx.x;
  if (i >= n4) return;
  float4 v = *(const float4*)(src + (size_t)i * 4);
  uint2 pk;
  pk.x = f2bf(v.x) | (f2bf(v.y) << 16);
  pk.y = f2bf(v.z) | (f2bf(v.w) << 16);
  *(uint2*)(dst + (size_t)i * 4) = pk;
}

// ---------- MFMA GEMM: C(M,N) = A(M,K) * B(N,K)^T, bf16 inputs, fp32 acc ----------
// CMODE 1: bf16 out, col>>10 selects plane (QKV fused). CMODE 2: f32 out.
// 128x128 tile, 4 waves (2x2 of 64x64), 16x16x32 MFMA, BK=32, global_load_lds w=16.
template <int CMODE>
__global__ __launch_bounds__(256) void gemm_mfma(const us* __restrict__ A,
                                                 const us* __restrict__ B,
                                                 void* __restrict__ Cv,
                                                 int M, int N, int K) {
  __shared__ __bf16 As[128 * 32];
  __shared__ __bf16 Bs[128 * 32];
  const int tid = threadIdx.x;
  const int wid = tid >> 6;
  const int lane = tid & 63;
  const int bm = blockIdx.y * 128;
  const int bn = blockIdx.x * 128;
  const int wm = (wid & 1) * 64;
  const int wn = (wid >> 1) * 64;
  const int lr = lane & 15;
  const int quad = lane >> 4;

  floatx4 acc[4][4] = {};

  const int cb0 = wid * 128;  // this wave's first 16B-chunk of the 512-chunk tile

  for (int k0 = 0; k0 < K; k0 += 32) {
    __syncthreads();
#pragma unroll
    for (int p = 0; p < 2; ++p) {
      const int cb = cb0 + p * 64;       // wave-uniform chunk base
      const int c = cb + lane;           // this lane's chunk: row=c>>2, kchunk=c&3
      const us* ga = A + (size_t)(bm + (c >> 2)) * K + (k0 + (c & 3) * 8);
      const us* gb = B + (size_t)(bn + (c >> 2)) * K + (k0 + (c & 3) * 8);
      __builtin_amdgcn_global_load_lds((const __attribute__((address_space(1))) void*)ga,
                                       (__attribute__((address_space(3))) void*)(&As[cb * 8]),
                                       16, 0, 0);
      __builtin_amdgcn_global_load_lds((const __attribute__((address_space(1))) void*)gb,
                                       (__attribute__((address_space(3))) void*)(&Bs[cb * 8]),
                                       16, 0, 0);
    }
    __syncthreads();

    bf16x8 a[4], b[4];
#pragma unroll
    for (int i = 0; i < 4; ++i)
      a[i] = *(const bf16x8*)&As[(wm + i * 16 + lr) * 32 + quad * 8];
#pragma unroll
    for (int j = 0; j < 4; ++j)
      b[j] = *(const bf16x8*)&Bs[(wn + j * 16 + lr) * 32 + quad * 8];
#pragma unroll
    for (int i = 0; i < 4; ++i)
#pragma unroll
      for (int j = 0; j < 4; ++j)
        acc[i][j] = __builtin_amdgcn_mfma_f32_16x16x32_bf16(a[i], b[j], acc[i][j], 0, 0, 0);
  }

  // C/D layout (verified m89/m91): col = lane&15, row = quad*4 + reg
#pragma unroll
  for (int i = 0; i < 4; ++i) {
#pragma unroll
    for (int j = 0; j < 4; ++j) {
      const int col = bn + wn + j * 16 + lr;
#pragma unroll
      for (int r = 0; r < 4; ++r) {
        const int row = bm + wm + i * 16 + quad * 4 + r;
        const float v = acc[i][j][r];
        if constexpr (CMODE == 1) {
          us* dst = (us*)Cv;
          const int plane = col >> 10;
          dst[(size_t)plane * PLANE + (size_t)row * 1024 + (col & 1023)] = (us)f2bf(v);
        } else {
          ((float*)Cv)[(size_t)row * N + col] = v;
        }
      }
    }
  }
}

// ---------- causal flash attention: 4 lanes per query row ----------
#define ATQ 64
#define ATK 32
#define KSTR 72  /* us per LDS row: 64 + 8 pad */

__global__ __launch_bounds__(256) void attn_fwd(const us* __restrict__ Qb,
                                                const us* __restrict__ Kb,
                                                const us* __restrict__ Vb,
                                                us* __restrict__ Ob) {
  const int b = blockIdx.z;
  const int h = blockIdx.y;
  const int q0 = blockIdx.x * ATQ;
  const int t = threadIdx.x;
  const int r = t >> 2;   // local query row (0..63)
  const int dq = t & 3;   // dim quarter (16 dims each)
  const int s = q0 + r;

  __shared__ us Ks[ATK * KSTR];
  __shared__ us Vs[ATK * KSTR];

  float q[16];
  {
    const us* qp = Qb + ((size_t)(b * SEQ + s) * D_MODEL + h * D_HEAD + dq * 16);
    float t0[8], t1[8];
    unpack8(*(const uint4*)qp, t0);
    unpack8(*(const uint4*)(qp + 8), t1);
#pragma unroll
    for (int i = 0; i < 8; ++i) { q[i] = t0[i] * 0.125f; q[8 + i] = t1[i] * 0.125f; }
  }
  float o[16];
#pragma unroll
  for (int i = 0; i < 16; ++i) o[i] = 0.f;
  float m = -INFINITY, l = 0.f;

  const int kend = q0 + ATQ;
  const int srow = t >> 3;        // staging row (0..31)
  const int schunk = t & 7;       // staging 16B chunk (8 bf16)

  for (int k0 = 0; k0 < kend; k0 += ATK) {
    __syncthreads();
    {
      const size_t goff = (size_t)(b * SEQ + k0 + srow) * D_MODEL + h * D_HEAD + schunk * 8;
      *(uint4*)&Ks[srow * KSTR + schunk * 8] = *(const uint4*)(Kb + goff);
      *(uint4*)&Vs[srow * KSTR + schunk * 8] = *(const uint4*)(Vb + goff);
    }
    __syncthreads();

#pragma unroll 1
    for (int j = 0; j < ATK; ++j) {
      if (k0 + j > s) break;  // quad-uniform: all 4 lanes of a row break together
      float kf[16], vf[16];
      unpack8(*(const uint4*)&Ks[j * KSTR + dq * 16], kf);
      unpack8(*(const uint4*)&Ks[j * KSTR + dq * 16 + 8], kf + 8);
      float sc = 0.f;
#pragma unroll
      for (int i = 0; i < 16; ++i) sc += q[i] * kf[i];
      sc += __shfl_xor(sc, 1);
      sc += __shfl_xor(sc, 2);
      unpack8(*(const uint4*)&Vs[j * KSTR + dq * 16], vf);
      unpack8(*(const uint4*)&Vs[j * KSTR + dq * 16 + 8], vf + 8);
      if (sc <= m) {
        const float e = __expf(sc - m);
        l += e;
#pragma unroll
        for (int i = 0; i < 16; ++i) o[i] += e * vf[i];
      } else {
        const float c = __expf(m - sc);  // exp(-inf)=0 covers the first key
        m = sc;
        l = l * c + 1.f;
#pragma unroll
        for (int i = 0; i < 16; ++i) o[i] = o[i] * c + vf[i];
      }
    }
  }

  const float inv = 1.f / l;
  us* op = Ob + ((size_t)(b * SEQ + s) * D_MODEL + h * D_HEAD + dq * 16);
  uint4 p0, p1;
  p0.x = f2bf(o[0] * inv)  | (f2bf(o[1] * inv) << 16);
  p0.y = f2bf(o[2] * inv)  | (f2bf(o[3] * inv) << 16);
  p0.z = f2bf(o[4] * inv)  | (f2bf(o[5] * inv) << 16);
  p0.w = f2bf(o[6] * inv)  | (f2bf(o[7] * inv) << 16);
  p1.x = f2bf(o[8] * inv)  | (f2bf(o[9] * inv) << 16);
  p1.y = f2bf(o[10] * inv) | (f2bf(o[11] * inv) << 16);
  p1.z = f2bf(o[12] * inv) | (f2bf(o[13] * inv) << 16);
  p1.w = f2bf(o[14] * inv) | (f2bf(o[15] * inv) << 16);
  *(uint4*)op = p0;
  *(uint4*)(op + 8) = p1;
}

extern "C" void kernel_launch(void* const* d_in, const int* in_sizes, int n_in,
                              void* d_out, int out_size, void* d_ws, size_t ws_size,
                              hipStream_t stream) {
  const float* x  = (const float*)d_in[0];
  const float* Wq = (const float*)d_in[1];
  const float* Wk = (const float*)d_in[2];
  const float* Wv = (const float*)d_in[3];
  const float* Wo = (const float*)d_in[4];

  // ws (32 MB): [x_bf | Qb | Kb | Vb]; Ab aliases x_bf (x dead after QKV GEMM).
  us* xbf = (us*)d_ws;
  us* Qb  = xbf + PLANE;
  us* Kb  = xbf + 2 * PLANE;
  us* Vb  = xbf + 3 * PLANE;
  us* Ab  = xbf;
  // d_out (16 MB f32) doubles as scratch for fused Wqkv_bf (6 MB) until final GEMM.
  us* Wqkv = (us*)d_out;
  us* Wobf = Qb;  // Qb slot is dead after attention
  float* out = (float*)d_out;

  const int WN = D_MODEL * D_MODEL;  // 1M elems per weight

  convert_bf16<<<MTOT * D_MODEL / 4 / 256, 256, 0, stream>>>(x, xbf, MTOT * D_MODEL / 4);
  convert_bf16<<<WN / 4 / 256, 256, 0, stream>>>(Wq, Wqkv, WN / 4);
  convert_bf16<<<WN / 4 / 256, 256, 0, stream>>>(Wk, Wqkv + WN, WN / 4);
  convert_bf16<<<WN / 4 / 256, 256, 0, stream>>>(Wv, Wqkv + 2 * WN, WN / 4);

  // Fused QKV: C(4096, 3072) -> planes Qb/Kb/Vb
  gemm_mfma<1><<<dim3(3072 / 128, MTOT / 128), 256, 0, stream>>>(xbf, Wqkv, Qb, MTOT, 3072, D_MODEL);

  attn_fwd<<<dim3(SEQ / ATQ, NUM_HEADS, BATCH), 256, 0, stream>>>(Qb, Kb, Vb, Ab);

  convert_bf16<<<WN / 4 / 256, 256, 0, stream>>>(Wo, Wobf, WN / 4);
  gemm_mfma<2><<<dim3(D_MODEL / 128, MTOT / 128), 256, 0, stream>>>(Ab, Wobf, out, MTOT, D_MODEL, D_MODEL);
}

// Round 4
// 272.297 us; speedup vs baseline: 10.7104x; 4.2831x over previous
//
#include <hip/hip_runtime.h>

#define D_MODEL 1024
#define NUM_HEADS 16
#define D_HEAD 64
#define BATCH 2
#define SEQ 2048
#define MTOT (BATCH * SEQ) /* 4096 */
#define PLANE ((size_t)MTOT * D_MODEL)

typedef unsigned short us;
typedef __bf16 bf16x8 __attribute__((ext_vector_type(8)));
typedef float floatx4 __attribute__((ext_vector_type(4)));

// ---------- bf16 helpers ----------
__device__ __forceinline__ unsigned int f2bf(float f) {
  union { float f; unsigned int i; } v; v.f = f;
  unsigned int r = v.i + 0x7FFFu + ((v.i >> 16) & 1u); // RNE
  return r >> 16;
}

// ---------- f32 -> bf16 conversion ----------
__global__ __launch_bounds__(256) void convert_bf16(const float* __restrict__ src,
                                                    us* __restrict__ dst, int n4) {
  int i = blockIdx.x * 256 + threadIdx.x;
  if (i >= n4) return;
  float4 v = *(const float4*)(src + (size_t)i * 4);
  uint2 pk;
  pk.x = f2bf(v.x) | (f2bf(v.y) << 16);
  pk.y = f2bf(v.z) | (f2bf(v.w) << 16);
  *(uint2*)(dst + (size_t)i * 4) = pk;
}

// ---------- MFMA GEMM: C(M,N) = A(M,K) * B(N,K)^T, bf16 inputs, fp32 acc ----------
// CMODE 1: bf16 out, col>>10 selects plane (QKV fused). CMODE 2: f32 out.
template <int CMODE>
__global__ __launch_bounds__(256) void gemm_mfma(const us* __restrict__ A,
                                                 const us* __restrict__ B,
                                                 void* __restrict__ Cv,
                                                 int M, int N, int K) {
  __shared__ __bf16 As[128 * 32];
  __shared__ __bf16 Bs[128 * 32];
  const int tid = threadIdx.x;
  const int wid = tid >> 6;
  const int lane = tid & 63;
  const int bm = blockIdx.y * 128;
  const int bn = blockIdx.x * 128;
  const int wm = (wid & 1) * 64;
  const int wn = (wid >> 1) * 64;
  const int lr = lane & 15;
  const int quad = lane >> 4;

  floatx4 acc[4][4] = {};

  const int cb0 = wid * 128;

  for (int k0 = 0; k0 < K; k0 += 32) {
    __syncthreads();
#pragma unroll
    for (int p = 0; p < 2; ++p) {
      const int cb = cb0 + p * 64;
      const int c = cb + lane;
      const us* ga = A + (size_t)(bm + (c >> 2)) * K + (k0 + (c & 3) * 8);
      const us* gb = B + (size_t)(bn + (c >> 2)) * K + (k0 + (c & 3) * 8);
      __builtin_amdgcn_global_load_lds((const __attribute__((address_space(1))) void*)ga,
                                       (__attribute__((address_space(3))) void*)(&As[cb * 8]),
                                       16, 0, 0);
      __builtin_amdgcn_global_load_lds((const __attribute__((address_space(1))) void*)gb,
                                       (__attribute__((address_space(3))) void*)(&Bs[cb * 8]),
                                       16, 0, 0);
    }
    __syncthreads();

    bf16x8 a[4], b[4];
#pragma unroll
    for (int i = 0; i < 4; ++i)
      a[i] = *(const bf16x8*)&As[(wm + i * 16 + lr) * 32 + quad * 8];
#pragma unroll
    for (int j = 0; j < 4; ++j)
      b[j] = *(const bf16x8*)&Bs[(wn + j * 16 + lr) * 32 + quad * 8];
#pragma unroll
    for (int i = 0; i < 4; ++i)
#pragma unroll
      for (int j = 0; j < 4; ++j)
        acc[i][j] = __builtin_amdgcn_mfma_f32_16x16x32_bf16(a[i], b[j], acc[i][j], 0, 0, 0);
  }

  // C/D layout: col = lane&15, row = quad*4 + reg (verified r3)
#pragma unroll
  for (int i = 0; i < 4; ++i) {
#pragma unroll
    for (int j = 0; j < 4; ++j) {
      const int col = bn + wn + j * 16 + lr;
#pragma unroll
      for (int r = 0; r < 4; ++r) {
        const int row = bm + wm + i * 16 + quad * 4 + r;
        const float v = acc[i][j][r];
        if constexpr (CMODE == 1) {
          us* dst = (us*)Cv;
          const int plane = col >> 10;
          dst[(size_t)plane * PLANE + (size_t)row * 1024 + (col & 1023)] = (us)f2bf(v);
        } else {
          ((float*)Cv)[(size_t)row * N + col] = v;
        }
      }
    }
  }
}

// ---------- MFMA causal flash attention ----------
// Block: one (b, h, 64-row Q tile); 4 waves x 16 q-rows. K-tile = 64 keys.
// QK^T and PV on mfma_f32_16x16x32_bf16; online softmax in C-layout;
// P transforms C-layout -> A-layout via wave-private LDS round-trip (m120).
#define ASTR 72 /* us per LDS row: 64 + 8 pad; 144B = 16B-aligned, 2-way banks */

__global__ __launch_bounds__(256) void attn_mfma(const us* __restrict__ Qb,
                                                 const us* __restrict__ Kb,
                                                 const us* __restrict__ Vb,
                                                 us* __restrict__ Ob) {
  const int b = blockIdx.z;
  const int h = blockIdx.y;
  const int q0 = blockIdx.x * 64;
  const int tid = threadIdx.x;
  const int wid = tid >> 6;
  const int lane = tid & 63;
  const int lr = lane & 15;
  const int quad = lane >> 4;

  __shared__ us Ks[64 * ASTR];          // K tile [key][dim]
  __shared__ us Vt[64 * ASTR];          // V tile transposed [dim][key]
  __shared__ us Ps[4 * 16 * ASTR];      // per-wave P [qrow][key]

  // Q A-frags: A[m=lr][k=quad*8+j], dims kc*32
  const us* qrow = Qb + ((size_t)(b * SEQ + q0 + wid * 16 + lr) * D_MODEL + h * D_HEAD);
  const bf16x8 qa0 = *(const bf16x8*)(qrow + quad * 8);
  const bf16x8 qa1 = *(const bf16x8*)(qrow + 32 + quad * 8);

  floatx4 oacc[4] = {};                 // [nt]: rows quad*4+r, col d = nt*16+lr
  float m_i[4] = {-1e30f, -1e30f, -1e30f, -1e30f};
  float l_i[4] = {0.f, 0.f, 0.f, 0.f};

  const int ntiles = blockIdx.x + 1;
  us* const pw = &Ps[wid * 16 * ASTR];

  for (int t = 0; t < ntiles; ++t) {
    const int k0 = t * 64;
    __syncthreads();
    // stage K [key][dim]: coalesced 16B loads
#pragma unroll
    for (int p = 0; p < 2; ++p) {
      const int c = tid + p * 256;
      const int row = c >> 3, col = (c & 7) * 8;
      *(uint4*)&Ks[row * ASTR + col] =
          *(const uint4*)(Kb + (size_t)(b * SEQ + k0 + row) * D_MODEL + h * D_HEAD + col);
    }
    // stage V transposed: key = lane (conflict-free LDS writes; scattered 16B
    // global reads served by L2/L3 — Q/K/V total 24 MB, fully L3-resident)
#pragma unroll
    for (int p = 0; p < 2; ++p) {
      const int key = tid & 63;
      const int dc = (tid >> 6) + p * 4;
      uint4 v = *(const uint4*)(Vb + (size_t)(b * SEQ + k0 + key) * D_MODEL + h * D_HEAD + dc * 8);
      unsigned int w[4] = {v.x, v.y, v.z, v.w};
#pragma unroll
      for (int j = 0; j < 4; ++j) {
        Vt[(dc * 8 + 2 * j) * ASTR + key] = (us)(w[j] & 0xFFFFu);
        Vt[(dc * 8 + 2 * j + 1) * ASTR + key] = (us)(w[j] >> 16);
      }
    }
    __syncthreads();

    // ---- S = Q K^T (scores in C-layout) ----
    floatx4 sc[4] = {};
#pragma unroll
    for (int jt = 0; jt < 4; ++jt) {
      const bf16x8 kb0 = *(const bf16x8*)&Ks[(jt * 16 + lr) * ASTR + quad * 8];
      const bf16x8 kb1 = *(const bf16x8*)&Ks[(jt * 16 + lr) * ASTR + 32 + quad * 8];
      sc[jt] = __builtin_amdgcn_mfma_f32_16x16x32_bf16(qa0, kb0, sc[jt], 0, 0, 0);
      sc[jt] = __builtin_amdgcn_mfma_f32_16x16x32_bf16(qa1, kb1, sc[jt], 0, 0, 0);
    }
    // scale; causal mask only on the diagonal tile (k0 == q0, wave-uniform)
#pragma unroll
    for (int jt = 0; jt < 4; ++jt)
#pragma unroll
      for (int r = 0; r < 4; ++r) sc[jt][r] *= 0.125f;
    if (k0 == q0) {
      const int qloc = wid * 16 + quad * 4;  // + r
#pragma unroll
      for (int jt = 0; jt < 4; ++jt) {
        const int key = jt * 16 + lr;
#pragma unroll
        for (int r = 0; r < 4; ++r)
          if (key > qloc + r) sc[jt][r] = -1e30f;
      }
    }

    // ---- online softmax (rows = quad*4+r, replicated across 16 lanes) ----
    float rmax[4], rsum[4], alpha[4];
#pragma unroll
    for (int r = 0; r < 4; ++r)
      rmax[r] = fmaxf(fmaxf(sc[0][r], sc[1][r]), fmaxf(sc[2][r], sc[3][r]));
#pragma unroll
    for (int s = 1; s < 16; s <<= 1)
#pragma unroll
      for (int r = 0; r < 4; ++r) rmax[r] = fmaxf(rmax[r], __shfl_xor(rmax[r], s));
#pragma unroll
    for (int r = 0; r < 4; ++r) {
      const float mn = fmaxf(m_i[r], rmax[r]);
      alpha[r] = __expf(m_i[r] - mn);
      m_i[r] = mn;
      rsum[r] = 0.f;
    }
#pragma unroll
    for (int jt = 0; jt < 4; ++jt)
#pragma unroll
      for (int r = 0; r < 4; ++r) {
        const float p = __expf(sc[jt][r] - m_i[r]);
        sc[jt][r] = p;
        rsum[r] += p;
      }
#pragma unroll
    for (int s = 1; s < 16; s <<= 1)
#pragma unroll
      for (int r = 0; r < 4; ++r) rsum[r] += __shfl_xor(rsum[r], s);
#pragma unroll
    for (int r = 0; r < 4; ++r) l_i[r] = l_i[r] * alpha[r] + rsum[r];
#pragma unroll
    for (int nt = 0; nt < 4; ++nt)
#pragma unroll
      for (int r = 0; r < 4; ++r) oacc[nt][r] *= alpha[r];

    // ---- P: C-layout -> LDS [qrow][key] -> A-layout frags (wave-private) ----
#pragma unroll
    for (int jt = 0; jt < 4; ++jt)
#pragma unroll
      for (int r = 0; r < 4; ++r)
        pw[(quad * 4 + r) * ASTR + jt * 16 + lr] = (us)f2bf(sc[jt][r]);
    const bf16x8 pa0 = *(const bf16x8*)&pw[lr * ASTR + quad * 8];
    const bf16x8 pa1 = *(const bf16x8*)&pw[lr * ASTR + 32 + quad * 8];

    // ---- O += P V  (B-frags = row reads of Vt) ----
#pragma unroll
    for (int nt = 0; nt < 4; ++nt) {
      const bf16x8 vb0 = *(const bf16x8*)&Vt[(nt * 16 + lr) * ASTR + quad * 8];
      const bf16x8 vb1 = *(const bf16x8*)&Vt[(nt * 16 + lr) * ASTR + 32 + quad * 8];
      oacc[nt] = __builtin_amdgcn_mfma_f32_16x16x32_bf16(pa0, vb0, oacc[nt], 0, 0, 0);
      oacc[nt] = __builtin_amdgcn_mfma_f32_16x16x32_bf16(pa1, vb1, oacc[nt], 0, 0, 0);
    }
  }

  // ---- epilogue: O / l, bf16 out ----
  float inv[4];
#pragma unroll
  for (int r = 0; r < 4; ++r) inv[r] = 1.f / l_i[r];
#pragma unroll
  for (int r = 0; r < 4; ++r) {
    const int q = q0 + wid * 16 + quad * 4 + r;
    us* op = Ob + (size_t)(b * SEQ + q) * D_MODEL + h * D_HEAD + lr;
#pragma unroll
    for (int nt = 0; nt < 4; ++nt) op[nt * 16] = (us)f2bf(oacc[nt][r] * inv[r]);
  }
}

extern "C" void kernel_launch(void* const* d_in, const int* in_sizes, int n_in,
                              void* d_out, int out_size, void* d_ws, size_t ws_size,
                              hipStream_t stream) {
  const float* x  = (const float*)d_in[0];
  const float* Wq = (const float*)d_in[1];
  const float* Wk = (const float*)d_in[2];
  const float* Wv = (const float*)d_in[3];
  const float* Wo = (const float*)d_in[4];

  // ws (32 MB): [x_bf | Qb | Kb | Vb]; Ab aliases x_bf (x dead after QKV GEMM).
  us* xbf = (us*)d_ws;
  us* Qb  = xbf + PLANE;
  us* Kb  = xbf + 2 * PLANE;
  us* Vb  = xbf + 3 * PLANE;
  us* Ab  = xbf;
  // d_out (16 MB f32) doubles as scratch for fused Wqkv_bf (6 MB) until final GEMM.
  us* Wqkv = (us*)d_out;
  us* Wobf = Qb;  // Qb slot dead after attention
  float* out = (float*)d_out;

  const int WN = D_MODEL * D_MODEL;

  convert_bf16<<<MTOT * D_MODEL / 4 / 256, 256, 0, stream>>>(x, xbf, MTOT * D_MODEL / 4);
  convert_bf16<<<WN / 4 / 256, 256, 0, stream>>>(Wq, Wqkv, WN / 4);
  convert_bf16<<<WN / 4 / 256, 256, 0, stream>>>(Wk, Wqkv + WN, WN / 4);
  convert_bf16<<<WN / 4 / 256, 256, 0, stream>>>(Wv, Wqkv + 2 * WN, WN / 4);

  gemm_mfma<1><<<dim3(3072 / 128, MTOT / 128), 256, 0, stream>>>(xbf, Wqkv, Qb, MTOT, 3072, D_MODEL);

  attn_mfma<<<dim3(SEQ / 64, NUM_HEADS, BATCH), 256, 0, stream>>>(Qb, Kb, Vb, Ab);

  convert_bf16<<<WN / 4 / 256, 256, 0, stream>>>(Wo, Wobf, WN / 4);
  gemm_mfma<2><<<dim3(D_MODEL / 128, MTOT / 128), 256, 0, stream>>>(Ab, Wobf, out, MTOT, D_MODEL, D_MODEL);
}